// Round 12
// baseline (268.604 us; speedup 1.0000x reference)
//
#include <hip/hip_runtime.h>
#include <hip/hip_bf16.h>

#define SEQ 1024
#define DM 512
#define D2 1024
#define NSTATE 16
#define BATCH 8
#define ROWS (BATCH * SEQ)
#define EPSF 1e-5f

typedef __attribute__((ext_vector_type(8))) short bf16x8;
typedef __attribute__((ext_vector_type(4))) float f32x4;

#define AS1 __attribute__((address_space(1)))
#define AS3 __attribute__((address_space(3)))

__device__ __forceinline__ void gll16(const void* g, void* l) {
    __builtin_amdgcn_global_load_lds(
        (const AS1 unsigned int*)(uintptr_t)g,
        (AS3 unsigned int*)(unsigned int)(uintptr_t)l, 16, 0, 0);
}

__device__ __forceinline__ float sigmoidf_(float x) {
    return 1.f / (1.f + __expf(-x));
}
__device__ __forceinline__ unsigned short f2bf(float f) {
    __hip_bfloat16 h = __float2bfloat16(f);
    unsigned short r;
    __builtin_memcpy(&r, &h, 2);
    return r;
}

// ------------------------------------------- merged weight-prep (7 jobs)
__global__ __launch_bounds__(256) void prep_all(
    const float* s0, const float* s1, const float* s2, const float* s3,
    const float* s4, const float* s5, const float* s6,
    __hip_bfloat16* d0, __hip_bfloat16* d1, __hip_bfloat16* d2,
    __hip_bfloat16* d3, __hip_bfloat16* d4, __hip_bfloat16* d5,
    __hip_bfloat16* d6) {
    const int j = blockIdx.z;
    int R, C;
    const float* src;
    __hip_bfloat16* dst;
    switch (j) {
        case 0: src = s0; dst = d0; R = 512; C = 1024; break;
        case 1: src = s1; dst = d1; R = 512; C = 1024; break;
        case 2: src = s2; dst = d2; R = 1024; C = 1024; break;
        case 3: src = s3; dst = d3; R = 1024; C = 1024; break;
        case 4: src = s4; dst = d4; R = 1024; C = 512; break;
        case 5: src = s5; dst = d5; R = 1024; C = 16; break;
        default: src = s6; dst = d6; R = 1024; C = 16; break;
    }
    int c0 = blockIdx.x * 32, r0 = blockIdx.y * 32;
    if (c0 >= C || r0 >= R) return;
    __shared__ float tile[32][33];
    int tx = threadIdx.x & 31, ty = threadIdx.x >> 5;
#pragma unroll
    for (int p = 0; p < 4; ++p) {
        int r = r0 + ty + p * 8, c = c0 + tx;
        if (r < R && c < C) tile[ty + p * 8][tx] = src[(size_t)r * C + c];
    }
    __syncthreads();
#pragma unroll
    for (int p = 0; p < 4; ++p) {
        int c = c0 + ty + p * 8, r = r0 + tx;
        if (r < R && c < C)
            dst[(size_t)c * R + r] = __float2bfloat16(tile[tx][ty + p * 8]);
    }
}

__global__ __launch_bounds__(256) void convw_k(const float* __restrict__ cw,
                                               __hip_bfloat16* __restrict__ wk) {
    int idx = blockIdx.x * 256 + threadIdx.x;
    float a = cw[(size_t)idx * 3 + 0];
    float b = cw[(size_t)idx * 3 + 1];
    float c = cw[(size_t)idx * 3 + 2];
    wk[idx] = __float2bfloat16(a);
    wk[(size_t)SEQ * SEQ + idx] = __float2bfloat16(b);
    wk[(size_t)2 * SEQ * SEQ + idx] = __float2bfloat16(c);
}

// ---------------------------------------------------------------- rmsnorm
__global__ __launch_bounds__(256) void rmsnorm_k(
    const float* __restrict__ x, const float* __restrict__ w,
    __hip_bfloat16* __restrict__ o) {
    int row = blockIdx.x;
    const float* xr = x + (size_t)row * DM;
    __hip_bfloat16* orow = o + (size_t)row * DM;
    int t = threadIdx.x;
    float v0 = xr[t];
    float v1 = xr[t + 256];
    float ss = v0 * v0 + v1 * v1;
#pragma unroll
    for (int off = 32; off; off >>= 1) ss += __shfl_down(ss, off, 64);
    __shared__ float parts[4];
    if ((t & 63) == 0) parts[t >> 6] = ss;
    __syncthreads();
    float tot = parts[0] + parts[1] + parts[2] + parts[3];
    float rs = rsqrtf(tot * (1.f / DM) + EPSF);
    orow[t] = __float2bfloat16(v0 * rs * w[t]);
    orow[t + 256] = __float2bfloat16(v1 * rs * w[t + 256]);
}

// ------------------------------------------------------ MFMA bf16 GEMM
// C[M,N] = epi( A[M,K] @ Bt[N,K]^T + bias ); 128x128 tile, 4 waves (2x2,
// 64x64/wave), BK=128: 8 fat phases (4 barrier-free substeps x 16 MFMA),
// 2-buffer LDS (128 KB), counted vmcnt(16) 2-barrier scheme, XCD swizzle.
// Swizzle per 64-col half: slot s of row r holds src block (s&8)|((s&7)^(r&7)).
// EPI: 1 bf16; 3 ssm tail->bf16; 4 f32;
//      5 dual: cols<D2 transposed x_proj store, cols>=D2 silu->outp2.
template <int EPI>
__global__ __launch_bounds__(256) void mgemm(
    const __hip_bfloat16* __restrict__ A, const __hip_bfloat16* __restrict__ Bt,
    const float* __restrict__ bias, void* __restrict__ outp,
    void* __restrict__ outp2, const float* __restrict__ bias2,
    const __hip_bfloat16* __restrict__ uptr,
    const __hip_bfloat16* __restrict__ resid, const float* __restrict__ bcv,
    int M, int N, int K) {
    __shared__ __align__(16) __hip_bfloat16 As[2][128 * 128];
    __shared__ __align__(16) __hip_bfloat16 Bs[2][128 * 128];
    const int nbx = gridDim.x;
    int lin = blockIdx.y * nbx + blockIdx.x;
    int chunk = (nbx * gridDim.y) >> 3;
    int wg = (lin & 7) * chunk + (lin >> 3);
    const int n0 = (wg % nbx) * 128, m0 = (wg / nbx) * 128;
    const int t = threadIdx.x, lane = t & 63, w = t >> 6;
    const int wr = w >> 1, wc = w & 1;
    const int l15 = lane & 15, l4 = lane >> 4;

    // staging sources: 8 macros per matrix, pre-swizzled (rule #21)
    const __hip_bfloat16* srcA[8];
    const __hip_bfloat16* srcB[8];
#pragma unroll
    for (int p = 0; p < 8; ++p) {
        int q = p * 256 + t, r = q >> 4;
        int cs = (q & 8) | ((q & 7) ^ (r & 7));
        srcA[p] = A + (size_t)(m0 + r) * K + cs * 8;
        srcB[p] = Bt + (size_t)(n0 + r) * K + cs * 8;
    }

    // fragment read offsets: block b = kk*4 + l4 of row
    int offA[4][4], offB[4][4];
#pragma unroll
    for (int i = 0; i < 4; ++i) {
        int ra = wr * 64 + i * 16 + l15;
        int rb = wc * 64 + i * 16 + l15;
#pragma unroll
        for (int kk = 0; kk < 4; ++kk) {
            int b = kk * 4 + l4;
            offA[i][kk] = (ra * 16 + (b & 8) + ((b & 7) ^ (ra & 7))) * 8;
            offB[i][kk] = (rb * 16 + (b & 8) + ((b & 7) ^ (rb & 7))) * 8;
        }
    }

#define MSTAGE(BUF, K0)                                           \
    {                                                             \
        _Pragma("unroll") for (int p = 0; p < 8; ++p) {           \
            gll16(srcA[p] + (K0), &As[BUF][(p * 256 + w * 64) * 8]); \
            gll16(srcB[p] + (K0), &Bs[BUF][(p * 256 + w * 64) * 8]); \
        }                                                         \
    }

    f32x4 acc[4][4] = {};
    const int NT = K >> 7;
    MSTAGE(0, 0);

#pragma unroll 1
    for (int kt = 0; kt < NT; ++kt) {
        const int buf = kt & 1;
        if (kt + 1 < NT) {
            MSTAGE(buf ^ 1, (kt + 1) * 128);
            asm volatile("s_waitcnt vmcnt(16)" ::: "memory");  // buf complete
        } else {
            asm volatile("s_waitcnt vmcnt(0)" ::: "memory");
        }
        __builtin_amdgcn_s_barrier();  // A: buf ready for all waves
        __builtin_amdgcn_sched_barrier(0);
#pragma unroll
        for (int kk = 0; kk < 4; ++kk) {
            bf16x8 af[4], bv[4];
#pragma unroll
            for (int i = 0; i < 4; ++i) {
                af[i] = *(const bf16x8*)&As[buf][offA[i][kk]];
                bv[i] = *(const bf16x8*)&Bs[buf][offB[i][kk]];
            }
            __builtin_amdgcn_s_setprio(1);
#pragma unroll
            for (int i = 0; i < 4; ++i)
#pragma unroll
                for (int j = 0; j < 4; ++j)
                    acc[i][j] = __builtin_amdgcn_mfma_f32_16x16x32_bf16(
                        af[i], bv[j], acc[i][j], 0, 0, 0);
            __builtin_amdgcn_s_setprio(0);
        }
        if (kt + 1 < NT) {
            __builtin_amdgcn_s_barrier();  // B: buf free for overwrite
            __builtin_amdgcn_sched_barrier(0);
        }
    }
#undef MSTAGE

    const int mb = m0 + wr * 64, nb = n0 + wc * 64;
#pragma unroll
    for (int i = 0; i < 4; ++i) {
#pragma unroll
        for (int j = 0; j < 4; ++j) {
            int ngl = nb + j * 16 + l15;
            if (EPI == 5) {
                if (nb < D2) {  // wave-uniform
                    float bj = bias[ngl];
                    int b = m0 >> 10;
                    int ibase = (mb & (SEQ - 1)) + i * 16 + l4 * 4;
                    ushort4 pk;
                    pk.x = f2bf(acc[i][j][0] + bj);
                    pk.y = f2bf(acc[i][j][1] + bj);
                    pk.z = f2bf(acc[i][j][2] + bj);
                    pk.w = f2bf(acc[i][j][3] + bj);
                    *(ushort4*)((__hip_bfloat16*)outp +
                                ((size_t)b * D2 + ngl) * SEQ + ibase) = pk;
                } else {
                    int ng2 = ngl - D2;
                    float bj = bias2[ng2];
#pragma unroll
                    for (int r = 0; r < 4; ++r) {
                        int mg = mb + i * 16 + l4 * 4 + r;
                        float c = acc[i][j][r] + bj;
                        ((__hip_bfloat16*)outp2)[(size_t)mg * D2 + ng2] =
                            __float2bfloat16(c * sigmoidf_(c));
                    }
                }
            } else {
                float bj = bias[ngl];
#pragma unroll
                for (int r = 0; r < 4; ++r) {
                    int mg = mb + i * 16 + l4 * 4 + r;
                    size_t ro = (size_t)mg * N + ngl;
                    float c = acc[i][j][r] + bj;
                    if (EPI == 1) {
                        ((__hip_bfloat16*)outp)[ro] = __float2bfloat16(c);
                    } else if (EPI == 3) {
                        float sp = (c > 20.f) ? c : log1pf(__expf(c));
                        float xs = __bfloat162float(uptr[ro]) * sp * bcv[mg];
                        float v = __bfloat162float(resid[ro]) *
                                  (xs * sigmoidf_(xs));
                        ((__hip_bfloat16*)outp)[ro] = __float2bfloat16(v);
                    } else {
                        ((float*)outp)[ro] = c;
                    }
                }
            }
        }
    }
}

// ------------------------------------------------------------ conv (MFMA)
// 128x128 tile, W+X LDS 2-buffer, counted vmcnt(8), 2-barrier, halo prologue.
__global__ __launch_bounds__(256) void conv_mfma(
    const __hip_bfloat16* __restrict__ wk,  // [3][SEQ][SEQ]
    const __hip_bfloat16* __restrict__ Xt,  // [B][D2][SEQ]
    const float* __restrict__ cb, __hip_bfloat16* __restrict__ outp) {
    __shared__ __align__(16) __hip_bfloat16 Ws[2][3][128 * 32];
    __shared__ __align__(16) __hip_bfloat16 Xs[2][128 * 32];
    __shared__ __align__(16) __hip_bfloat16 Xh[2][SEQ];
    int lin = blockIdx.x + 8 * blockIdx.y + 64 * blockIdx.z;
    int wg = (lin & 7) * 64 + (lin >> 3);
    const int n0 = (wg & 7) * 128;         // h tile
    const int m0 = ((wg >> 3) & 7) * 128;  // o tile
    const int z = wg >> 6;                 // batch
    const int t = threadIdx.x, lane = t & 63, w = t >> 6;
    const int wr = w >> 1, wc = w & 1;
    const int l15 = lane & 15, l4 = lane >> 4;
    const __hip_bfloat16* Xtb = Xt + (size_t)z * D2 * SEQ;

    {
        int which = t >> 7;
        int col = (t & 127) * 8;
        int h = n0 - 1 + which * 129;
        uint4 v = make_uint4(0u, 0u, 0u, 0u);
        if (h >= 0 && h < D2)
            v = *(const uint4*)(Xtb + (size_t)h * SEQ + col);
        *(uint4*)&Xh[which][col] = v;
    }

    int rowp[2], cbw[2];
#pragma unroll
    for (int p = 0; p < 2; ++p) {
        int blk = p * 256 + t;
        rowp[p] = blk >> 2;
        cbw[p] = (blk & 3) ^ ((rowp[p] >> 1) & 3);
    }
    const __hip_bfloat16* wsrc[2][3];
    const __hip_bfloat16* xsrc[2];
#pragma unroll
    for (int p = 0; p < 2; ++p) {
#pragma unroll
        for (int tp = 0; tp < 3; ++tp)
            wsrc[p][tp] = wk + (size_t)tp * SEQ * SEQ +
                          (size_t)(m0 + rowp[p]) * SEQ + cbw[p] * 8;
        xsrc[p] = Xtb + (size_t)(n0 + rowp[p]) * SEQ + cbw[p] * 8;
    }
    const int dst0 = (w * 64) * 8, dst1 = (256 + w * 64) * 8;

    int offA[4];
#pragma unroll
    for (int i = 0; i < 4; ++i) {
        int ra = wr * 64 + i * 16 + l15;
        offA[i] = (ra * 4 + (l4 ^ ((ra >> 1) & 3))) * 8;
    }

#define CSTAGE(BUF, K0)                              \
    {                                                \
        gll16(wsrc[0][0] + (K0), &Ws[BUF][0][dst0]); \
        gll16(wsrc[1][0] + (K0), &Ws[BUF][0][dst1]); \
        gll16(wsrc[0][1] + (K0), &Ws[BUF][1][dst0]); \
        gll16(wsrc[1][1] + (K0), &Ws[BUF][1][dst1]); \
        gll16(wsrc[0][2] + (K0), &Ws[BUF][2][dst0]); \
        gll16(wsrc[1][2] + (K0), &Ws[BUF][2][dst1]); \
        gll16(xsrc[0] + (K0), &Xs[BUF][dst0]);       \
        gll16(xsrc[1] + (K0), &Xs[BUF][dst1]);       \
    }

    f32x4 acc[4][4] = {};
    CSTAGE(0, 0);
    asm volatile("s_waitcnt lgkmcnt(0)" ::: "memory");  // halo ds_writes

#pragma unroll 1
    for (int kt = 0; kt < 32; ++kt) {
        const int k0 = kt * 32;
        const int buf = kt & 1;
        if (kt + 1 < 32) {
            CSTAGE(buf ^ 1, (kt + 1) * 32);
            asm volatile("s_waitcnt vmcnt(8)" ::: "memory");
        } else {
            asm volatile("s_waitcnt vmcnt(0)" ::: "memory");
        }
        __builtin_amdgcn_s_barrier();
        __builtin_amdgcn_sched_barrier(0);
        bf16x8 aw[3][4];
#pragma unroll
        for (int tp = 0; tp < 3; ++tp)
#pragma unroll
            for (int i = 0; i < 4; ++i)
                aw[tp][i] = *(const bf16x8*)&Ws[buf][tp][offA[i]];
        __builtin_amdgcn_s_setprio(1);
#pragma unroll
        for (int j = 0; j < 4; ++j) {
#pragma unroll
            for (int tp = 0; tp < 3; ++tp) {
                int rb = wc * 64 + j * 16 + l15 + tp;
                int r = rb - 1;
                const __hip_bfloat16* src =
                    &Xs[buf][(r * 4 + (l4 ^ ((r >> 1) & 3))) * 8];
                if (rb == 0) src = &Xh[0][k0 + l4 * 8];
                if (rb == 129) src = &Xh[1][k0 + l4 * 8];
                bf16x8 bvx = *(const bf16x8*)src;
#pragma unroll
                for (int i = 0; i < 4; ++i)
                    acc[i][j] = __builtin_amdgcn_mfma_f32_16x16x32_bf16(
                        aw[tp][i], bvx, acc[i][j], 0, 0, 0);
            }
        }
        __builtin_amdgcn_s_setprio(0);
        if (kt + 1 < 32) {
            __builtin_amdgcn_s_barrier();
            __builtin_amdgcn_sched_barrier(0);
        }
    }
#undef CSTAGE

    const int mb = m0 + wr * 64, nb = n0 + wc * 64;
    size_t ob = (size_t)z * SEQ * D2;
#pragma unroll
    for (int i = 0; i < 4; ++i)
#pragma unroll
        for (int j = 0; j < 4; ++j)
#pragma unroll
            for (int r = 0; r < 4; ++r) {
                int mg = mb + i * 16 + l4 * 4 + r;
                int ng = nb + j * 16 + l15;
                float c = acc[i][j][r] + cb[mg];
                outp[ob + (size_t)mg * D2 + ng] =
                    __float2bfloat16(c * sigmoidf_(c));
            }
}

// ------------------------------------------------- bc via skinny MFMA GEMM
__global__ __launch_bounds__(256) void bc2_k(
    const __hip_bfloat16* __restrict__ u, const __hip_bfloat16* __restrict__ fcT,
    const float* __restrict__ b2, const float* __restrict__ b3,
    float* __restrict__ bc) {
    __shared__ __align__(16) __hip_bfloat16 Bl[32 * 1024];
    __shared__ __align__(16) __hip_bfloat16 As[3][128 * 32];
    const int m0 = blockIdx.x * 128;
    const int t = threadIdx.x, lane = t & 63, w = t >> 6;
    const int l15 = lane & 15, l4 = lane >> 4;

#pragma unroll
    for (int it = 0; it < 16; ++it) {
        int q = it * 256 + t;
        int n = q >> 7, blk = q & 127;
        uint4 v = *(const uint4*)(fcT + (size_t)n * 1024 + blk * 8);
        *(uint4*)&Bl[(n * 128 + (blk ^ (n & 7))) * 8] = v;
    }

    const int r0_ = t >> 2, c0_ = (t & 3) ^ ((r0_ >> 1) & 3);
    const int bq = 256 + t, r1_ = bq >> 2, c1_ = (bq & 3) ^ ((r1_ >> 1) & 3);
    const __hip_bfloat16* gA0 = u + (size_t)(m0 + r0_) * 1024 + c0_ * 8;
    const __hip_bfloat16* gA1 = u + (size_t)(m0 + r1_) * 1024 + c1_ * 8;
    const int d0 = (w * 64) * 8, d1 = (256 + w * 64) * 8;

    int offA[2];
#pragma unroll
    for (int i = 0; i < 2; ++i) {
        int ra = w * 32 + i * 16 + l15;
        offA[i] = (ra * 4 + (l4 ^ ((ra >> 1) & 3))) * 8;
    }

#define BSTAGE(BUF, K0)                  \
    {                                    \
        gll16(gA0 + (K0), &As[BUF][d0]); \
        gll16(gA1 + (K0), &As[BUF][d1]); \
    }

    f32x4 acc[2][2] = {};
    unsigned curb = 0, nxtb = 1, thdb = 2;
    BSTAGE(0, 0);
    BSTAGE(1, 32);
    asm volatile("s_waitcnt vmcnt(2)" ::: "memory");
    __builtin_amdgcn_s_barrier();
    __builtin_amdgcn_sched_barrier(0);

#pragma unroll 1
    for (int kt = 0; kt < 32; ++kt) {
        const bool st = (kt + 2 < 32);
        if (st) BSTAGE(thdb, (kt + 2) * 32);
        bf16x8 af[2], bf[2];
#pragma unroll
        for (int i = 0; i < 2; ++i) af[i] = *(const bf16x8*)&As[curb][offA[i]];
#pragma unroll
        for (int nj = 0; nj < 2; ++nj) {
            int n = nj * 16 + l15;
            int blk = (kt * 4 + l4) ^ (n & 7);
            bf[nj] = *(const bf16x8*)&Bl[(n * 128 + blk) * 8];
        }
#pragma unroll
        for (int i = 0; i < 2; ++i)
#pragma unroll
            for (int nj = 0; nj < 2; ++nj)
                acc[i][nj] = __builtin_amdgcn_mfma_f32_16x16x32_bf16(
                    af[i], bf[nj], acc[i][nj], 0, 0, 0);
        if (kt + 1 < 32) {
            if (st)
                asm volatile("s_waitcnt vmcnt(2)" ::: "memory");
            else
                asm volatile("s_waitcnt vmcnt(0)" ::: "memory");
            __builtin_amdgcn_s_barrier();
            __builtin_amdgcn_sched_barrier(0);
        }
        unsigned tb = curb;
        curb = nxtb;
        nxtb = thdb;
        thdb = tb;
    }
#undef BSTAGE

    float bb2 = b2[l15], bb3 = b3[l15];
#pragma unroll
    for (int i = 0; i < 2; ++i)
#pragma unroll
        for (int r = 0; r < 4; ++r) {
            float Bv = acc[i][0][r] + bb2;
            float Cv = acc[i][1][r] + bb3;
            float p = Bv * Cv;
            p += __shfl_xor(p, 1, 64);
            p += __shfl_xor(p, 2, 64);
            p += __shfl_xor(p, 4, 64);
            p += __shfl_xor(p, 8, 64);
            if (l15 == 0)
                bc[m0 + w * 32 + i * 16 + l4 * 4 + r] = p;
        }
}

// ----------------------------------------------------------------- launch
extern "C" void kernel_launch(void* const* d_in, const int* in_sizes, int n_in,
                              void* d_out, int out_size, void* d_ws,
                              size_t ws_size, hipStream_t stream) {
    const float* x = (const float*)d_in[0];
    const float* norm_w = (const float*)d_in[1];
    const float* inp_w = (const float*)d_in[2];
    const float* inp_b = (const float*)d_in[3];
    const float* conv_w = (const float*)d_in[4];
    const float* conv_b = (const float*)d_in[5];
    const float* convlin_w = (const float*)d_in[6];
    const float* convlin_b = (const float*)d_in[7];
    const float* fc1_w = (const float*)d_in[8];
    const float* fc1_b = (const float*)d_in[9];
    const float* fc2_w = (const float*)d_in[10];
    const float* fc2_b = (const float*)d_in[11];
    const float* fc3_w = (const float*)d_in[12];
    const float* fc3_b = (const float*)d_in[13];
    const float* D_w = (const float*)d_in[14];
    const float* D_b = (const float*)d_in[15];
    const float* out_w = (const float*)d_in[16];
    const float* out_b = (const float*)d_in[17];
    float* out = (float*)d_out;

    __hip_bfloat16* xnb = (__hip_bfloat16*)d_ws;          // [ROWS][DM]
    __hip_bfloat16* xt = xnb + (size_t)ROWS * DM;         // [B][D2][SEQ]
    __hip_bfloat16* cvo = xt + (size_t)BATCH * D2 * SEQ;  // conv out / act
    __hip_bfloat16* u = cvo + (size_t)ROWS * D2;          // [ROWS][D2]
    __hip_bfloat16* resid = u + (size_t)ROWS * D2;        // [ROWS][D2]
    __hip_bfloat16* Wcat = resid + (size_t)ROWS * D2;     // [2*D2][DM]
    __hip_bfloat16* clT = Wcat + (size_t)2 * D2 * DM;     // [D2][D2]
    __hip_bfloat16* fc1T = clT + (size_t)D2 * D2;         // [D2][D2]
    __hip_bfloat16* outT = fc1T + (size_t)D2 * D2;        // [DM][D2]
    __hip_bfloat16* wk = outT + (size_t)DM * D2;          // [3][SEQ][SEQ]
    __hip_bfloat16* fcT = wk + (size_t)3 * SEQ * SEQ;     // [32][D2]
    float* bcb = (float*)(fcT + (size_t)32 * D2);         // [ROWS]

    prep_all<<<dim3(32, 32, 7), 256, 0, stream>>>(
        inp_w, D_w, convlin_w, fc1_w, out_w, fc2_w, fc3_w, Wcat,
        Wcat + (size_t)D2 * DM, clT, fc1T, outT, fcT, fcT + (size_t)16 * D2);
    convw_k<<<SEQ * SEQ / 256, 256, 0, stream>>>(conv_w, wk);
    // 1. xn = rmsnorm(x) (bf16)
    rmsnorm_k<<<ROWS, 256, 0, stream>>>(x, norm_w, xnb);
    // 2+6. fused: x_proj -> Xt (transposed) AND resid = silu(xn@D_w+b)
    mgemm<5><<<dim3(2 * D2 / 128, ROWS / 128), 256, 0, stream>>>(
        xnb, Wcat, inp_b, xt, resid, D_b, nullptr, nullptr, nullptr, ROWS,
        2 * D2, DM);
    // 3. conv + bias + silu -> cvo[b][o][h]
    conv_mfma<<<dim3(D2 / 128, SEQ / 128, BATCH), 256, 0, stream>>>(
        wk, xt, conv_b, cvo);
    // 4. u = cvo @ convlin + b
    mgemm<1><<<dim3(D2 / 128, ROWS / 128), 256, 0, stream>>>(
        cvo, clT, convlin_b, u, nullptr, nullptr, nullptr, nullptr, nullptr,
        ROWS, D2, D2);
    // 5. bc via skinny MFMA
    bc2_k<<<ROWS / 128, 256, 0, stream>>>(u, fcT, fc2_b, fc3_b, bcb);
    // 7. delta GEMM + ssm tail -> act (reuses cvo)
    mgemm<3><<<dim3(D2 / 128, ROWS / 128), 256, 0, stream>>>(
        u, fc1T, fc1_b, cvo, nullptr, nullptr, u, resid, bcb, ROWS, D2, D2);
    // 8. out = act @ out_w + out_b (f32)
    mgemm<4><<<dim3(DM / 128, ROWS / 128), 256, 0, stream>>>(
        cvo, outT, out_b, out, nullptr, nullptr, nullptr, nullptr, nullptr,
        ROWS, DM, D2);
}

// Round 13
// 227.819 us; speedup vs baseline: 1.1790x; 1.1790x over previous
//
#include <hip/hip_runtime.h>
#include <hip/hip_bf16.h>

#define SEQ 1024
#define DM 512
#define D2 1024
#define NSTATE 16
#define BATCH 8
#define ROWS (BATCH * SEQ)
#define EPSF 1e-5f

typedef __attribute__((ext_vector_type(8))) short bf16x8;
typedef __attribute__((ext_vector_type(4))) float f32x4;

#define AS1 __attribute__((address_space(1)))
#define AS3 __attribute__((address_space(3)))

__device__ __forceinline__ void gll16(const void* g, void* l) {
    __builtin_amdgcn_global_load_lds(
        (const AS1 unsigned int*)(uintptr_t)g,
        (AS3 unsigned int*)(unsigned int)(uintptr_t)l, 16, 0, 0);
}

__device__ __forceinline__ float sigmoidf_(float x) {
    return 1.f / (1.f + __expf(-x));
}
__device__ __forceinline__ unsigned short f2bf(float f) {
    __hip_bfloat16 h = __float2bfloat16(f);
    unsigned short r;
    __builtin_memcpy(&r, &h, 2);
    return r;
}

// ------------------------------------------- merged weight-prep (7 jobs)
__global__ __launch_bounds__(256) void prep_all(
    const float* s0, const float* s1, const float* s2, const float* s3,
    const float* s4, const float* s5, const float* s6,
    __hip_bfloat16* d0, __hip_bfloat16* d1, __hip_bfloat16* d2,
    __hip_bfloat16* d3, __hip_bfloat16* d4, __hip_bfloat16* d5,
    __hip_bfloat16* d6) {
    const int j = blockIdx.z;
    int R, C;
    const float* src;
    __hip_bfloat16* dst;
    switch (j) {
        case 0: src = s0; dst = d0; R = 512; C = 1024; break;
        case 1: src = s1; dst = d1; R = 512; C = 1024; break;
        case 2: src = s2; dst = d2; R = 1024; C = 1024; break;
        case 3: src = s3; dst = d3; R = 1024; C = 1024; break;
        case 4: src = s4; dst = d4; R = 1024; C = 512; break;
        case 5: src = s5; dst = d5; R = 1024; C = 16; break;
        default: src = s6; dst = d6; R = 1024; C = 16; break;
    }
    int c0 = blockIdx.x * 32, r0 = blockIdx.y * 32;
    if (c0 >= C || r0 >= R) return;
    __shared__ float tile[32][33];
    int tx = threadIdx.x & 31, ty = threadIdx.x >> 5;
#pragma unroll
    for (int p = 0; p < 4; ++p) {
        int r = r0 + ty + p * 8, c = c0 + tx;
        if (r < R && c < C) tile[ty + p * 8][tx] = src[(size_t)r * C + c];
    }
    __syncthreads();
#pragma unroll
    for (int p = 0; p < 4; ++p) {
        int c = c0 + ty + p * 8, r = r0 + tx;
        if (r < R && c < C)
            dst[(size_t)c * R + r] = __float2bfloat16(tile[tx][ty + p * 8]);
    }
}

__global__ __launch_bounds__(256) void convw_k(const float* __restrict__ cw,
                                               __hip_bfloat16* __restrict__ wk) {
    int idx = blockIdx.x * 256 + threadIdx.x;
    float a = cw[(size_t)idx * 3 + 0];
    float b = cw[(size_t)idx * 3 + 1];
    float c = cw[(size_t)idx * 3 + 2];
    wk[idx] = __float2bfloat16(a);
    wk[(size_t)SEQ * SEQ + idx] = __float2bfloat16(b);
    wk[(size_t)2 * SEQ * SEQ + idx] = __float2bfloat16(c);
}

// ---------------------------------------------------------------- rmsnorm
__global__ __launch_bounds__(256) void rmsnorm_k(
    const float* __restrict__ x, const float* __restrict__ w,
    __hip_bfloat16* __restrict__ o) {
    int row = blockIdx.x;
    const float* xr = x + (size_t)row * DM;
    __hip_bfloat16* orow = o + (size_t)row * DM;
    int t = threadIdx.x;
    float v0 = xr[t];
    float v1 = xr[t + 256];
    float ss = v0 * v0 + v1 * v1;
#pragma unroll
    for (int off = 32; off; off >>= 1) ss += __shfl_down(ss, off, 64);
    __shared__ float parts[4];
    if ((t & 63) == 0) parts[t >> 6] = ss;
    __syncthreads();
    float tot = parts[0] + parts[1] + parts[2] + parts[3];
    float rs = rsqrtf(tot * (1.f / DM) + EPSF);
    orow[t] = __float2bfloat16(v0 * rs * w[t]);
    orow[t + 256] = __float2bfloat16(v1 * rs * w[t + 256]);
}

// ------------------------------------------------------ MFMA bf16 GEMM
// C[M,N] = epi( A[M,K] @ Bt[N,K]^T + bias ); 128x128 tile, 4 waves (2x2,
// 64x64/wave), BK=32, 5-DEEP gll pipeline: waited-on buffer was issued
// 3 phases earlier (~1000+ cyc in flight) so the end-of-phase vmcnt is
// latency-free. LDS 80 KB -> 2 blocks/CU. XCD swizzle.
// EPI: 1 bf16; 3 ssm tail->bf16; 4 f32;
//      5 dual: cols<D2 transposed x_proj store, cols>=D2 silu->outp2.
template <int EPI>
__global__ __launch_bounds__(256) void mgemm(
    const __hip_bfloat16* __restrict__ A, const __hip_bfloat16* __restrict__ Bt,
    const float* __restrict__ bias, void* __restrict__ outp,
    void* __restrict__ outp2, const float* __restrict__ bias2,
    const __hip_bfloat16* __restrict__ uptr,
    const __hip_bfloat16* __restrict__ resid, const float* __restrict__ bcv,
    int M, int N, int K) {
    __shared__ __align__(16) __hip_bfloat16 As[5][128 * 32];
    __shared__ __align__(16) __hip_bfloat16 Bs[5][128 * 32];
    const int nbx = gridDim.x;
    int lin = blockIdx.y * nbx + blockIdx.x;
    int chunk = (nbx * gridDim.y) >> 3;
    int wg = (lin & 7) * chunk + (lin >> 3);
    const int n0 = (wg % nbx) * 128, m0 = (wg / nbx) * 128;
    const int t = threadIdx.x, lane = t & 63, w = t >> 6;
    const int wr = w >> 1, wc = w & 1;
    const int l15 = lane & 15, l4 = lane >> 4;

    const int r0_ = t >> 2, c0_ = (t & 3) ^ ((r0_ >> 1) & 3);
    const int b1 = 256 + t, r1_ = b1 >> 2, c1_ = (b1 & 3) ^ ((r1_ >> 1) & 3);
    const __hip_bfloat16* gA0 = A + (size_t)(m0 + r0_) * K + c0_ * 8;
    const __hip_bfloat16* gA1 = A + (size_t)(m0 + r1_) * K + c1_ * 8;
    const __hip_bfloat16* gB0 = Bt + (size_t)(n0 + r0_) * K + c0_ * 8;
    const __hip_bfloat16* gB1 = Bt + (size_t)(n0 + r1_) * K + c1_ * 8;
    const int d0 = (w * 64) * 8, d1 = (256 + w * 64) * 8;

    int offA[4], offB[4];
#pragma unroll
    for (int i = 0; i < 4; ++i) {
        int ra = wr * 64 + i * 16 + l15;
        offA[i] = (ra * 4 + (l4 ^ ((ra >> 1) & 3))) * 8;
        int rb = wc * 64 + i * 16 + l15;
        offB[i] = (rb * 4 + (l4 ^ ((rb >> 1) & 3))) * 8;
    }

#define MSTAGE(BUF, K0)                  \
    {                                    \
        gll16(gA0 + (K0), &As[BUF][d0]); \
        gll16(gA1 + (K0), &As[BUF][d1]); \
        gll16(gB0 + (K0), &Bs[BUF][d0]); \
        gll16(gB1 + (K0), &Bs[BUF][d1]); \
    }

    f32x4 acc[4][4] = {};
    const int NT = K >> 5;  // 16 or 32; NT >= 5 assumed
    MSTAGE(0, 0);
    MSTAGE(1, 32);
    MSTAGE(2, 64);
    MSTAGE(3, 96);
    asm volatile("s_waitcnt vmcnt(12)" ::: "memory");  // buf0 complete
    __builtin_amdgcn_s_barrier();
    __builtin_amdgcn_sched_barrier(0);

#pragma unroll 1
    for (int kt = 0; kt < NT; ++kt) {
        const int buf = kt % 5;
        if (kt + 4 < NT) MSTAGE((kt + 4) % 5, (kt + 4) * 32);
        bf16x8 af[4], bv[4];
#pragma unroll
        for (int i = 0; i < 4; ++i) {
            af[i] = *(const bf16x8*)&As[buf][offA[i]];
            bv[i] = *(const bf16x8*)&Bs[buf][offB[i]];
        }
        __builtin_amdgcn_s_setprio(1);
#pragma unroll
        for (int i = 0; i < 4; ++i)
#pragma unroll
            for (int j = 0; j < 4; ++j)
                acc[i][j] = __builtin_amdgcn_mfma_f32_16x16x32_bf16(
                    af[i], bv[j], acc[i][j], 0, 0, 0);
        __builtin_amdgcn_s_setprio(0);
        if (kt + 1 < NT) {
            // need buf(kt+1) complete; stages kt+2..min(kt+4,NT-1) may remain
            int rem = NT - 2 - kt;
            if (rem >= 3)
                asm volatile("s_waitcnt vmcnt(12)" ::: "memory");
            else if (rem == 2)
                asm volatile("s_waitcnt vmcnt(8)" ::: "memory");
            else if (rem == 1)
                asm volatile("s_waitcnt vmcnt(4)" ::: "memory");
            else
                asm volatile("s_waitcnt vmcnt(0)" ::: "memory");
            __builtin_amdgcn_s_barrier();
            __builtin_amdgcn_sched_barrier(0);
        }
    }
#undef MSTAGE

    const int mb = m0 + wr * 64, nb = n0 + wc * 64;
#pragma unroll
    for (int i = 0; i < 4; ++i) {
#pragma unroll
        for (int j = 0; j < 4; ++j) {
            int ngl = nb + j * 16 + l15;
            if (EPI == 5) {
                if (nb < D2) {  // wave-uniform
                    float bj = bias[ngl];
                    int b = m0 >> 10;
                    int ibase = (mb & (SEQ - 1)) + i * 16 + l4 * 4;
                    ushort4 pk;
                    pk.x = f2bf(acc[i][j][0] + bj);
                    pk.y = f2bf(acc[i][j][1] + bj);
                    pk.z = f2bf(acc[i][j][2] + bj);
                    pk.w = f2bf(acc[i][j][3] + bj);
                    *(ushort4*)((__hip_bfloat16*)outp +
                                ((size_t)b * D2 + ngl) * SEQ + ibase) = pk;
                } else {
                    int ng2 = ngl - D2;
                    float bj = bias2[ng2];
#pragma unroll
                    for (int r = 0; r < 4; ++r) {
                        int mg = mb + i * 16 + l4 * 4 + r;
                        float c = acc[i][j][r] + bj;
                        ((__hip_bfloat16*)outp2)[(size_t)mg * D2 + ng2] =
                            __float2bfloat16(c * sigmoidf_(c));
                    }
                }
            } else {
                float bj = bias[ngl];
#pragma unroll
                for (int r = 0; r < 4; ++r) {
                    int mg = mb + i * 16 + l4 * 4 + r;
                    size_t ro = (size_t)mg * N + ngl;
                    float c = acc[i][j][r] + bj;
                    if (EPI == 1) {
                        ((__hip_bfloat16*)outp)[ro] = __float2bfloat16(c);
                    } else if (EPI == 3) {
                        float sp = (c > 20.f) ? c : log1pf(__expf(c));
                        float xs = __bfloat162float(uptr[ro]) * sp * bcv[mg];
                        float v = __bfloat162float(resid[ro]) *
                                  (xs * sigmoidf_(xs));
                        ((__hip_bfloat16*)outp)[ro] = __float2bfloat16(v);
                    } else {
                        ((float*)outp)[ro] = c;
                    }
                }
            }
        }
    }
}

// ------------------------------------------------------------ conv (MFMA)
// 128x128 tile, W+X LDS 2-buffer, counted vmcnt(8), 2-barrier, halo
// prologue. (R11 version — 33% MfmaUtil, fat phases cover latency.)
__global__ __launch_bounds__(256) void conv_mfma(
    const __hip_bfloat16* __restrict__ wk,  // [3][SEQ][SEQ]
    const __hip_bfloat16* __restrict__ Xt,  // [B][D2][SEQ]
    const float* __restrict__ cb, __hip_bfloat16* __restrict__ outp) {
    __shared__ __align__(16) __hip_bfloat16 Ws[2][3][128 * 32];
    __shared__ __align__(16) __hip_bfloat16 Xs[2][128 * 32];
    __shared__ __align__(16) __hip_bfloat16 Xh[2][SEQ];
    int lin = blockIdx.x + 8 * blockIdx.y + 64 * blockIdx.z;
    int wg = (lin & 7) * 64 + (lin >> 3);
    const int n0 = (wg & 7) * 128;         // h tile
    const int m0 = ((wg >> 3) & 7) * 128;  // o tile
    const int z = wg >> 6;                 // batch
    const int t = threadIdx.x, lane = t & 63, w = t >> 6;
    const int wr = w >> 1, wc = w & 1;
    const int l15 = lane & 15, l4 = lane >> 4;
    const __hip_bfloat16* Xtb = Xt + (size_t)z * D2 * SEQ;

    {
        int which = t >> 7;
        int col = (t & 127) * 8;
        int h = n0 - 1 + which * 129;
        uint4 v = make_uint4(0u, 0u, 0u, 0u);
        if (h >= 0 && h < D2)
            v = *(const uint4*)(Xtb + (size_t)h * SEQ + col);
        *(uint4*)&Xh[which][col] = v;
    }

    int rowp[2], cbw[2];
#pragma unroll
    for (int p = 0; p < 2; ++p) {
        int blk = p * 256 + t;
        rowp[p] = blk >> 2;
        cbw[p] = (blk & 3) ^ ((rowp[p] >> 1) & 3);
    }
    const __hip_bfloat16* wsrc[2][3];
    const __hip_bfloat16* xsrc[2];
#pragma unroll
    for (int p = 0; p < 2; ++p) {
#pragma unroll
        for (int tp = 0; tp < 3; ++tp)
            wsrc[p][tp] = wk + (size_t)tp * SEQ * SEQ +
                          (size_t)(m0 + rowp[p]) * SEQ + cbw[p] * 8;
        xsrc[p] = Xtb + (size_t)(n0 + rowp[p]) * SEQ + cbw[p] * 8;
    }
    const int dst0 = (w * 64) * 8, dst1 = (256 + w * 64) * 8;

    int offA[4];
#pragma unroll
    for (int i = 0; i < 4; ++i) {
        int ra = wr * 64 + i * 16 + l15;
        offA[i] = (ra * 4 + (l4 ^ ((ra >> 1) & 3))) * 8;
    }

#define CSTAGE(BUF, K0)                              \
    {                                                \
        gll16(wsrc[0][0] + (K0), &Ws[BUF][0][dst0]); \
        gll16(wsrc[1][0] + (K0), &Ws[BUF][0][dst1]); \
        gll16(wsrc[0][1] + (K0), &Ws[BUF][1][dst0]); \
        gll16(wsrc[1][1] + (K0), &Ws[BUF][1][dst1]); \
        gll16(wsrc[0][2] + (K0), &Ws[BUF][2][dst0]); \
        gll16(wsrc[1][2] + (K0), &Ws[BUF][2][dst1]); \
        gll16(xsrc[0] + (K0), &Xs[BUF][dst0]);       \
        gll16(xsrc[1] + (K0), &Xs[BUF][dst1]);       \
    }

    f32x4 acc[4][4] = {};
    CSTAGE(0, 0);
    asm volatile("s_waitcnt lgkmcnt(0)" ::: "memory");  // halo ds_writes

#pragma unroll 1
    for (int kt = 0; kt < 32; ++kt) {
        const int k0 = kt * 32;
        const int buf = kt & 1;
        if (kt + 1 < 32) {
            CSTAGE(buf ^ 1, (kt + 1) * 32);
            asm volatile("s_waitcnt vmcnt(8)" ::: "memory");
        } else {
            asm volatile("s_waitcnt vmcnt(0)" ::: "memory");
        }
        __builtin_amdgcn_s_barrier();
        __builtin_amdgcn_sched_barrier(0);
        bf16x8 aw[3][4];
#pragma unroll
        for (int tp = 0; tp < 3; ++tp)
#pragma unroll
            for (int i = 0; i < 4; ++i)
                aw[tp][i] = *(const bf16x8*)&Ws[buf][tp][offA[i]];
        __builtin_amdgcn_s_setprio(1);
#pragma unroll
        for (int j = 0; j < 4; ++j) {
#pragma unroll
            for (int tp = 0; tp < 3; ++tp) {
                int rb = wc * 64 + j * 16 + l15 + tp;
                int r = rb - 1;
                const __hip_bfloat16* src =
                    &Xs[buf][(r * 4 + (l4 ^ ((r >> 1) & 3))) * 8];
                if (rb == 0) src = &Xh[0][k0 + l4 * 8];
                if (rb == 129) src = &Xh[1][k0 + l4 * 8];
                bf16x8 bvx = *(const bf16x8*)src;
#pragma unroll
                for (int i = 0; i < 4; ++i)
                    acc[i][j] = __builtin_amdgcn_mfma_f32_16x16x32_bf16(
                        aw[tp][i], bvx, acc[i][j], 0, 0, 0);
            }
        }
        __builtin_amdgcn_s_setprio(0);
        if (kt + 1 < 32) {
            __builtin_amdgcn_s_barrier();
            __builtin_amdgcn_sched_barrier(0);
        }
    }
#undef CSTAGE

    const int mb = m0 + wr * 64, nb = n0 + wc * 64;
    size_t ob = (size_t)z * SEQ * D2;
#pragma unroll
    for (int i = 0; i < 4; ++i)
#pragma unroll
        for (int j = 0; j < 4; ++j)
#pragma unroll
            for (int r = 0; r < 4; ++r) {
                int mg = mb + i * 16 + l4 * 4 + r;
                int ng = nb + j * 16 + l15;
                float c = acc[i][j][r] + cb[mg];
                outp[ob + (size_t)mg * D2 + ng] =
                    __float2bfloat16(c * sigmoidf_(c));
            }
}

// ------------------------------------------------- bc via skinny MFMA GEMM
__global__ __launch_bounds__(256) void bc2_k(
    const __hip_bfloat16* __restrict__ u, const __hip_bfloat16* __restrict__ fcT,
    const float* __restrict__ b2, const float* __restrict__ b3,
    float* __restrict__ bc) {
    __shared__ __align__(16) __hip_bfloat16 Bl[32 * 1024];
    __shared__ __align__(16) __hip_bfloat16 As[3][128 * 32];
    const int m0 = blockIdx.x * 128;
    const int t = threadIdx.x, lane = t & 63, w = t >> 6;
    const int l15 = lane & 15, l4 = lane >> 4;

#pragma unroll
    for (int it = 0; it < 16; ++it) {
        int q = it * 256 + t;
        int n = q >> 7, blk = q & 127;
        uint4 v = *(const uint4*)(fcT + (size_t)n * 1024 + blk * 8);
        *(uint4*)&Bl[(n * 128 + (blk ^ (n & 7))) * 8] = v;
    }

    const int r0_ = t >> 2, c0_ = (t & 3) ^ ((r0_ >> 1) & 3);
    const int bq = 256 + t, r1_ = bq >> 2, c1_ = (bq & 3) ^ ((r1_ >> 1) & 3);
    const __hip_bfloat16* gA0 = u + (size_t)(m0 + r0_) * 1024 + c0_ * 8;
    const __hip_bfloat16* gA1 = u + (size_t)(m0 + r1_) * 1024 + c1_ * 8;
    const int d0 = (w * 64) * 8, d1 = (256 + w * 64) * 8;

    int offA[2];
#pragma unroll
    for (int i = 0; i < 2; ++i) {
        int ra = w * 32 + i * 16 + l15;
        offA[i] = (ra * 4 + (l4 ^ ((ra >> 1) & 3))) * 8;
    }

#define BSTAGE(BUF, K0)                  \
    {                                    \
        gll16(gA0 + (K0), &As[BUF][d0]); \
        gll16(gA1 + (K0), &As[BUF][d1]); \
    }

    f32x4 acc[2][2] = {};
    unsigned curb = 0, nxtb = 1, thdb = 2;
    BSTAGE(0, 0);
    BSTAGE(1, 32);
    asm volatile("s_waitcnt vmcnt(2)" ::: "memory");
    __builtin_amdgcn_s_barrier();
    __builtin_amdgcn_sched_barrier(0);

#pragma unroll 1
    for (int kt = 0; kt < 32; ++kt) {
        const bool st = (kt + 2 < 32);
        if (st) BSTAGE(thdb, (kt + 2) * 32);
        bf16x8 af[2], bf[2];
#pragma unroll
        for (int i = 0; i < 2; ++i) af[i] = *(const bf16x8*)&As[curb][offA[i]];
#pragma unroll
        for (int nj = 0; nj < 2; ++nj) {
            int n = nj * 16 + l15;
            int blk = (kt * 4 + l4) ^ (n & 7);
            bf[nj] = *(const bf16x8*)&Bl[(n * 128 + blk) * 8];
        }
#pragma unroll
        for (int i = 0; i < 2; ++i)
#pragma unroll
            for (int nj = 0; nj < 2; ++nj)
                acc[i][nj] = __builtin_amdgcn_mfma_f32_16x16x32_bf16(
                    af[i], bf[nj], acc[i][nj], 0, 0, 0);
        if (kt + 1 < 32) {
            if (st)
                asm volatile("s_waitcnt vmcnt(2)" ::: "memory");
            else
                asm volatile("s_waitcnt vmcnt(0)" ::: "memory");
            __builtin_amdgcn_s_barrier();
            __builtin_amdgcn_sched_barrier(0);
        }
        unsigned tb = curb;
        curb = nxtb;
        nxtb = thdb;
        thdb = tb;
    }
#undef BSTAGE

    float bb2 = b2[l15], bb3 = b3[l15];
#pragma unroll
    for (int i = 0; i < 2; ++i)
#pragma unroll
        for (int r = 0; r < 4; ++r) {
            float Bv = acc[i][0][r] + bb2;
            float Cv = acc[i][1][r] + bb3;
            float p = Bv * Cv;
            p += __shfl_xor(p, 1, 64);
            p += __shfl_xor(p, 2, 64);
            p += __shfl_xor(p, 4, 64);
            p += __shfl_xor(p, 8, 64);
            if (l15 == 0)
                bc[m0 + w * 32 + i * 16 + l4 * 4 + r] = p;
        }
}

// ----------------------------------------------------------------- launch
extern "C" void kernel_launch(void* const* d_in, const int* in_sizes, int n_in,
                              void* d_out, int out_size, void* d_ws,
                              size_t ws_size, hipStream_t stream) {
    const float* x = (const float*)d_in[0];
    const float* norm_w = (const float*)d_in[1];
    const float* inp_w = (const float*)d_in[2];
    const float* inp_b = (const float*)d_in[3];
    const float* conv_w = (const float*)d_in[4];
    const float* conv_b = (const float*)d_in[5];
    const float* convlin_w = (const float*)d_in[6];
    const float* convlin_b = (const float*)d_in[7];
    const float* fc1_w = (const float*)d_in[8];
    const float* fc1_b = (const float*)d_in[9];
    const float* fc2_w = (const float*)d_in[10];
    const float* fc2_b = (const float*)d_in[11];
    const float* fc3_w = (const float*)d_in[12];
    const float* fc3_b = (const float*)d_in[13];
    const float* D_w = (const float*)d_in[14];
    const float* D_b = (const float*)d_in[15];
    const float* out_w = (const float*)d_in[16];
    const float* out_b = (const float*)d_in[17];
    float* out = (float*)d_out;

    __hip_bfloat16* xnb = (__hip_bfloat16*)d_ws;          // [ROWS][DM]
    __hip_bfloat16* xt = xnb + (size_t)ROWS * DM;         // [B][D2][SEQ]
    __hip_bfloat16* cvo = xt + (size_t)BATCH * D2 * SEQ;  // conv out / act
    __hip_bfloat16* u = cvo + (size_t)ROWS * D2;          // [ROWS][D2]
    __hip_bfloat16* resid = u + (size_t)ROWS * D2;        // [ROWS][D2]
    __hip_bfloat16* Wcat = resid + (size_t)ROWS * D2;     // [2*D2][DM]
    __hip_bfloat16* clT = Wcat + (size_t)2 * D2 * DM;     // [D2][D2]
    __hip_bfloat16* fc1T = clT + (size_t)D2 * D2;         // [D2][D2]
    __hip_bfloat16* outT = fc1T + (size_t)D2 * D2;        // [DM][D2]
    __hip_bfloat16* wk = outT + (size_t)DM * D2;          // [3][SEQ][SEQ]
    __hip_bfloat16* fcT = wk + (size_t)3 * SEQ * SEQ;     // [32][D2]
    float* bcb = (float*)(fcT + (size_t)32 * D2);         // [ROWS]

    prep_all<<<dim3(32, 32, 7), 256, 0, stream>>>(
        inp_w, D_w, convlin_w, fc1_w, out_w, fc2_w, fc3_w, Wcat,
        Wcat + (size_t)D2 * DM, clT, fc1T, outT, fcT, fcT + (size_t)16 * D2);
    convw_k<<<SEQ * SEQ / 256, 256, 0, stream>>>(conv_w, wk);
    // 1. xn = rmsnorm(x) (bf16)
    rmsnorm_k<<<ROWS, 256, 0, stream>>>(x, norm_w, xnb);
    // 2+6. fused: x_proj -> Xt (transposed) AND resid = silu(xn@D_w+b)
    mgemm<5><<<dim3(2 * D2 / 128, ROWS / 128), 256, 0, stream>>>(
        xnb, Wcat, inp_b, xt, resid, D_b, nullptr, nullptr, nullptr, ROWS,
        2 * D2, DM);
    // 3. conv + bias + silu -> cvo[b][o][h]
    conv_mfma<<<dim3(D2 / 128, SEQ / 128, BATCH), 256, 0, stream>>>(
        wk, xt, conv_b, cvo);
    // 4. u = cvo @ convlin + b
    mgemm<1><<<dim3(D2 / 128, ROWS / 128), 256, 0, stream>>>(
        cvo, clT, convlin_b, u, nullptr, nullptr, nullptr, nullptr, nullptr,
        ROWS, D2, D2);
    // 5. bc via skinny MFMA
    bc2_k<<<ROWS / 128, 256, 0, stream>>>(u, fcT, fc2_b, fc3_b, bcb);
    // 7. delta GEMM + ssm tail -> act (reuses cvo)
    mgemm<3><<<dim3(D2 / 128, ROWS / 128), 256, 0, stream>>>(
        u, fc1T, fc1_b, cvo, nullptr, nullptr, u, resid, bcb, ROWS, D2, D2);
    // 8. out = act @ out_w + out_b (f32)
    mgemm<4><<<dim3(DM / 128, ROWS / 128), 256, 0, stream>>>(
        cvo, outT, out_b, out, nullptr, nullptr, nullptr, nullptr, nullptr,
        ROWS, DM, D2);
}

// Round 14
// 223.101 us; speedup vs baseline: 1.2040x; 1.0211x over previous
//
#include <hip/hip_runtime.h>
#include <hip/hip_bf16.h>

#define SEQ 1024
#define DM 512
#define D2 1024
#define NSTATE 16
#define BATCH 8
#define ROWS (BATCH * SEQ)
#define EPSF 1e-5f

typedef __attribute__((ext_vector_type(8))) short bf16x8;
typedef __attribute__((ext_vector_type(4))) float f32x4;

#define AS1 __attribute__((address_space(1)))
#define AS3 __attribute__((address_space(3)))

__device__ __forceinline__ void gll16(const void* g, void* l) {
    __builtin_amdgcn_global_load_lds(
        (const AS1 unsigned int*)(uintptr_t)g,
        (AS3 unsigned int*)(unsigned int)(uintptr_t)l, 16, 0, 0);
}

__device__ __forceinline__ float sigmoidf_(float x) {
    return 1.f / (1.f + __expf(-x));
}
__device__ __forceinline__ unsigned short f2bf(float f) {
    __hip_bfloat16 h = __float2bfloat16(f);
    unsigned short r;
    __builtin_memcpy(&r, &h, 2);
    return r;
}

// ------------------------------------------- merged weight-prep (7 jobs)
__global__ __launch_bounds__(256) void prep_all(
    const float* s0, const float* s1, const float* s2, const float* s3,
    const float* s4, const float* s5, const float* s6,
    __hip_bfloat16* d0, __hip_bfloat16* d1, __hip_bfloat16* d2,
    __hip_bfloat16* d3, __hip_bfloat16* d4, __hip_bfloat16* d5,
    __hip_bfloat16* d6) {
    const int j = blockIdx.z;
    int R, C;
    const float* src;
    __hip_bfloat16* dst;
    switch (j) {
        case 0: src = s0; dst = d0; R = 512; C = 1024; break;
        case 1: src = s1; dst = d1; R = 512; C = 1024; break;
        case 2: src = s2; dst = d2; R = 1024; C = 1024; break;
        case 3: src = s3; dst = d3; R = 1024; C = 1024; break;
        case 4: src = s4; dst = d4; R = 1024; C = 512; break;
        case 5: src = s5; dst = d5; R = 1024; C = 16; break;
        default: src = s6; dst = d6; R = 1024; C = 16; break;
    }
    int c0 = blockIdx.x * 32, r0 = blockIdx.y * 32;
    if (c0 >= C || r0 >= R) return;
    __shared__ float tile[32][33];
    int tx = threadIdx.x & 31, ty = threadIdx.x >> 5;
#pragma unroll
    for (int p = 0; p < 4; ++p) {
        int r = r0 + ty + p * 8, c = c0 + tx;
        if (r < R && c < C) tile[ty + p * 8][tx] = src[(size_t)r * C + c];
    }
    __syncthreads();
#pragma unroll
    for (int p = 0; p < 4; ++p) {
        int c = c0 + ty + p * 8, r = r0 + tx;
        if (r < R && c < C)
            dst[(size_t)c * R + r] = __float2bfloat16(tile[tx][ty + p * 8]);
    }
}

__global__ __launch_bounds__(256) void convw_k(const float* __restrict__ cw,
                                               __hip_bfloat16* __restrict__ wk) {
    int idx = blockIdx.x * 256 + threadIdx.x;
    float a = cw[(size_t)idx * 3 + 0];
    float b = cw[(size_t)idx * 3 + 1];
    float c = cw[(size_t)idx * 3 + 2];
    wk[idx] = __float2bfloat16(a);
    wk[(size_t)SEQ * SEQ + idx] = __float2bfloat16(b);
    wk[(size_t)2 * SEQ * SEQ + idx] = __float2bfloat16(c);
}

// ---------------------------------------------------------------- rmsnorm
__global__ __launch_bounds__(256) void rmsnorm_k(
    const float* __restrict__ x, const float* __restrict__ w,
    __hip_bfloat16* __restrict__ o) {
    int row = blockIdx.x;
    const float* xr = x + (size_t)row * DM;
    __hip_bfloat16* orow = o + (size_t)row * DM;
    int t = threadIdx.x;
    float v0 = xr[t];
    float v1 = xr[t + 256];
    float ss = v0 * v0 + v1 * v1;
#pragma unroll
    for (int off = 32; off; off >>= 1) ss += __shfl_down(ss, off, 64);
    __shared__ float parts[4];
    if ((t & 63) == 0) parts[t >> 6] = ss;
    __syncthreads();
    float tot = parts[0] + parts[1] + parts[2] + parts[3];
    float rs = rsqrtf(tot * (1.f / DM) + EPSF);
    orow[t] = __float2bfloat16(v0 * rs * w[t]);
    orow[t + 256] = __float2bfloat16(v1 * rs * w[t + 256]);
}

// ------------------------------------------------------ MFMA bf16 GEMM
// C[M,N] = epi( A[M,K] @ Bt[N,K]^T + bias ); 128x128 tile, 4 waves (2x2,
// 64x64/wave). FAT PHASES: 2 K-steps (BK=32 each) per barrier-phase ->
// 32 MFMA + 16 ds_read per wave per phase (conv-morphic). 4 LDS buffers
// (64 KB, 2 blk/CU); stage-8 gll16 whose loads fly across the 32-MFMA
// body; ONE barrier per phase. XCD swizzle. KC = compile-time K.
// EPI: 1 bf16; 3 ssm tail->bf16; 4 f32;
//      5 dual: cols<D2 transposed x_proj store, cols>=D2 silu->outp2.
template <int EPI, int KC>
__global__ __launch_bounds__(256) void mgemm(
    const __hip_bfloat16* __restrict__ A, const __hip_bfloat16* __restrict__ Bt,
    const float* __restrict__ bias, void* __restrict__ outp,
    void* __restrict__ outp2, const float* __restrict__ bias2,
    const __hip_bfloat16* __restrict__ uptr,
    const __hip_bfloat16* __restrict__ resid, const float* __restrict__ bcv,
    int M, int N) {
    __shared__ __align__(16) __hip_bfloat16 As[4][128 * 32];
    __shared__ __align__(16) __hip_bfloat16 Bs[4][128 * 32];
    const int nbx = gridDim.x;
    int lin = blockIdx.y * nbx + blockIdx.x;
    int chunk = (nbx * gridDim.y) >> 3;
    int wg = (lin & 7) * chunk + (lin >> 3);
    const int n0 = (wg % nbx) * 128, m0 = (wg / nbx) * 128;
    const int t = threadIdx.x, lane = t & 63, w = t >> 6;
    const int wr = w >> 1, wc = w & 1;
    const int l15 = lane & 15, l4 = lane >> 4;

    const int r0_ = t >> 2, c0_ = (t & 3) ^ ((r0_ >> 1) & 3);
    const int b1 = 256 + t, r1_ = b1 >> 2, c1_ = (b1 & 3) ^ ((r1_ >> 1) & 3);
    const __hip_bfloat16* gA0 = A + (size_t)(m0 + r0_) * KC + c0_ * 8;
    const __hip_bfloat16* gA1 = A + (size_t)(m0 + r1_) * KC + c1_ * 8;
    const __hip_bfloat16* gB0 = Bt + (size_t)(n0 + r0_) * KC + c0_ * 8;
    const __hip_bfloat16* gB1 = Bt + (size_t)(n0 + r1_) * KC + c1_ * 8;
    const int d0 = (w * 64) * 8, d1 = (256 + w * 64) * 8;

    int offA[4], offB[4];
#pragma unroll
    for (int i = 0; i < 4; ++i) {
        int ra = wr * 64 + i * 16 + l15;
        offA[i] = (ra * 4 + (l4 ^ ((ra >> 1) & 3))) * 8;
        int rb = wc * 64 + i * 16 + l15;
        offB[i] = (rb * 4 + (l4 ^ ((rb >> 1) & 3))) * 8;
    }

#define MSTAGE(BUF, K0)                  \
    {                                    \
        gll16(gA0 + (K0), &As[BUF][d0]); \
        gll16(gA1 + (K0), &As[BUF][d1]); \
        gll16(gB0 + (K0), &Bs[BUF][d0]); \
        gll16(gB1 + (K0), &Bs[BUF][d1]); \
    }

    f32x4 acc[4][4] = {};
    constexpr int NT = KC >> 6;  // fat phases: 2 BK-steps each
    MSTAGE(0, 0);
    MSTAGE(1, 32);
    asm volatile("s_waitcnt vmcnt(0)" ::: "memory");
    __builtin_amdgcn_s_barrier();
    __builtin_amdgcn_sched_barrier(0);

#pragma unroll 1
    for (int p = 0; p < NT; ++p) {
        const int kA = 2 * p, kB = 2 * p + 1;
        const int bufA = kA & 3, bufB = kB & 3;
        if (p + 1 < NT) {
            MSTAGE((kA + 2) & 3, (kA + 2) * 32);
            MSTAGE((kB + 2) & 3, (kB + 2) * 32);
        }
        bf16x8 a0[4], b0[4], a1[4], b1v[4];
#pragma unroll
        for (int i = 0; i < 4; ++i) {
            a0[i] = *(const bf16x8*)&As[bufA][offA[i]];
            b0[i] = *(const bf16x8*)&Bs[bufA][offB[i]];
        }
#pragma unroll
        for (int i = 0; i < 4; ++i) {
            a1[i] = *(const bf16x8*)&As[bufB][offA[i]];
            b1v[i] = *(const bf16x8*)&Bs[bufB][offB[i]];
        }
        __builtin_amdgcn_s_setprio(1);
#pragma unroll
        for (int i = 0; i < 4; ++i)
#pragma unroll
            for (int j = 0; j < 4; ++j)
                acc[i][j] = __builtin_amdgcn_mfma_f32_16x16x32_bf16(
                    a0[i], b0[j], acc[i][j], 0, 0, 0);
#pragma unroll
        for (int i = 0; i < 4; ++i)
#pragma unroll
            for (int j = 0; j < 4; ++j)
                acc[i][j] = __builtin_amdgcn_mfma_f32_16x16x32_bf16(
                    a1[i], b1v[j], acc[i][j], 0, 0, 0);
        __builtin_amdgcn_s_setprio(0);
        if (p + 1 < NT) {
            asm volatile("s_waitcnt vmcnt(0)" ::: "memory");
            __builtin_amdgcn_s_barrier();
            __builtin_amdgcn_sched_barrier(0);
        }
    }
#undef MSTAGE

    const int mb = m0 + wr * 64, nb = n0 + wc * 64;
#pragma unroll
    for (int i = 0; i < 4; ++i) {
#pragma unroll
        for (int j = 0; j < 4; ++j) {
            int ngl = nb + j * 16 + l15;
            if (EPI == 5) {
                if (nb < D2) {  // wave-uniform
                    float bj = bias[ngl];
                    int b = m0 >> 10;
                    int ibase = (mb & (SEQ - 1)) + i * 16 + l4 * 4;
                    ushort4 pk;
                    pk.x = f2bf(acc[i][j][0] + bj);
                    pk.y = f2bf(acc[i][j][1] + bj);
                    pk.z = f2bf(acc[i][j][2] + bj);
                    pk.w = f2bf(acc[i][j][3] + bj);
                    *(ushort4*)((__hip_bfloat16*)outp +
                                ((size_t)b * D2 + ngl) * SEQ + ibase) = pk;
                } else {
                    int ng2 = ngl - D2;
                    float bj = bias2[ng2];
#pragma unroll
                    for (int r = 0; r < 4; ++r) {
                        int mg = mb + i * 16 + l4 * 4 + r;
                        float c = acc[i][j][r] + bj;
                        ((__hip_bfloat16*)outp2)[(size_t)mg * D2 + ng2] =
                            __float2bfloat16(c * sigmoidf_(c));
                    }
                }
            } else {
                float bj = bias[ngl];
#pragma unroll
                for (int r = 0; r < 4; ++r) {
                    int mg = mb + i * 16 + l4 * 4 + r;
                    size_t ro = (size_t)mg * N + ngl;
                    float c = acc[i][j][r] + bj;
                    if (EPI == 1) {
                        ((__hip_bfloat16*)outp)[ro] = __float2bfloat16(c);
                    } else if (EPI == 3) {
                        float sp = (c > 20.f) ? c : log1pf(__expf(c));
                        float xs = __bfloat162float(uptr[ro]) * sp * bcv[mg];
                        float v = __bfloat162float(resid[ro]) *
                                  (xs * sigmoidf_(xs));
                        ((__hip_bfloat16*)outp)[ro] = __float2bfloat16(v);
                    } else {
                        ((float*)outp)[ro] = c;
                    }
                }
            }
        }
    }
}

// ------------------------------------------------------------ conv (MFMA)
// 128x128 tile, W+X LDS 2-buffer, counted vmcnt(8), 2-barrier, halo
// prologue. (R11 version — best measured, 33% MfmaUtil.)
__global__ __launch_bounds__(256) void conv_mfma(
    const __hip_bfloat16* __restrict__ wk,  // [3][SEQ][SEQ]
    const __hip_bfloat16* __restrict__ Xt,  // [B][D2][SEQ]
    const float* __restrict__ cb, __hip_bfloat16* __restrict__ outp) {
    __shared__ __align__(16) __hip_bfloat16 Ws[2][3][128 * 32];
    __shared__ __align__(16) __hip_bfloat16 Xs[2][128 * 32];
    __shared__ __align__(16) __hip_bfloat16 Xh[2][SEQ];
    int lin = blockIdx.x + 8 * blockIdx.y + 64 * blockIdx.z;
    int wg = (lin & 7) * 64 + (lin >> 3);
    const int n0 = (wg & 7) * 128;         // h tile
    const int m0 = ((wg >> 3) & 7) * 128;  // o tile
    const int z = wg >> 6;                 // batch
    const int t = threadIdx.x, lane = t & 63, w = t >> 6;
    const int wr = w >> 1, wc = w & 1;
    const int l15 = lane & 15, l4 = lane >> 4;
    const __hip_bfloat16* Xtb = Xt + (size_t)z * D2 * SEQ;

    {
        int which = t >> 7;
        int col = (t & 127) * 8;
        int h = n0 - 1 + which * 129;
        uint4 v = make_uint4(0u, 0u, 0u, 0u);
        if (h >= 0 && h < D2)
            v = *(const uint4*)(Xtb + (size_t)h * SEQ + col);
        *(uint4*)&Xh[which][col] = v;
    }

    int rowp[2], cbw[2];
#pragma unroll
    for (int p = 0; p < 2; ++p) {
        int blk = p * 256 + t;
        rowp[p] = blk >> 2;
        cbw[p] = (blk & 3) ^ ((rowp[p] >> 1) & 3);
    }
    const __hip_bfloat16* wsrc[2][3];
    const __hip_bfloat16* xsrc[2];
#pragma unroll
    for (int p = 0; p < 2; ++p) {
#pragma unroll
        for (int tp = 0; tp < 3; ++tp)
            wsrc[p][tp] = wk + (size_t)tp * SEQ * SEQ +
                          (size_t)(m0 + rowp[p]) * SEQ + cbw[p] * 8;
        xsrc[p] = Xtb + (size_t)(n0 + rowp[p]) * SEQ + cbw[p] * 8;
    }
    const int dst0 = (w * 64) * 8, dst1 = (256 + w * 64) * 8;

    int offA[4];
#pragma unroll
    for (int i = 0; i < 4; ++i) {
        int ra = wr * 64 + i * 16 + l15;
        offA[i] = (ra * 4 + (l4 ^ ((ra >> 1) & 3))) * 8;
    }

#define CSTAGE(BUF, K0)                              \
    {                                                \
        gll16(wsrc[0][0] + (K0), &Ws[BUF][0][dst0]); \
        gll16(wsrc[1][0] + (K0), &Ws[BUF][0][dst1]); \
        gll16(wsrc[0][1] + (K0), &Ws[BUF][1][dst0]); \
        gll16(wsrc[1][1] + (K0), &Ws[BUF][1][dst1]); \
        gll16(wsrc[0][2] + (K0), &Ws[BUF][2][dst0]); \
        gll16(wsrc[1][2] + (K0), &Ws[BUF][2][dst1]); \
        gll16(xsrc[0] + (K0), &Xs[BUF][dst0]);       \
        gll16(xsrc[1] + (K0), &Xs[BUF][dst1]);       \
    }

    f32x4 acc[4][4] = {};
    CSTAGE(0, 0);
    asm volatile("s_waitcnt lgkmcnt(0)" ::: "memory");  // halo ds_writes

#pragma unroll 1
    for (int kt = 0; kt < 32; ++kt) {
        const int k0 = kt * 32;
        const int buf = kt & 1;
        if (kt + 1 < 32) {
            CSTAGE(buf ^ 1, (kt + 1) * 32);
            asm volatile("s_waitcnt vmcnt(8)" ::: "memory");
        } else {
            asm volatile("s_waitcnt vmcnt(0)" ::: "memory");
        }
        __builtin_amdgcn_s_barrier();
        __builtin_amdgcn_sched_barrier(0);
        bf16x8 aw[3][4];
#pragma unroll
        for (int tp = 0; tp < 3; ++tp)
#pragma unroll
            for (int i = 0; i < 4; ++i)
                aw[tp][i] = *(const bf16x8*)&Ws[buf][tp][offA[i]];
        __builtin_amdgcn_s_setprio(1);
#pragma unroll
        for (int j = 0; j < 4; ++j) {
#pragma unroll
            for (int tp = 0; tp < 3; ++tp) {
                int rb = wc * 64 + j * 16 + l15 + tp;
                int r = rb - 1;
                const __hip_bfloat16* src =
                    &Xs[buf][(r * 4 + (l4 ^ ((r >> 1) & 3))) * 8];
                if (rb == 0) src = &Xh[0][k0 + l4 * 8];
                if (rb == 129) src = &Xh[1][k0 + l4 * 8];
                bf16x8 bvx = *(const bf16x8*)src;
#pragma unroll
                for (int i = 0; i < 4; ++i)
                    acc[i][j] = __builtin_amdgcn_mfma_f32_16x16x32_bf16(
                        aw[tp][i], bvx, acc[i][j], 0, 0, 0);
            }
        }
        __builtin_amdgcn_s_setprio(0);
        if (kt + 1 < 32) {
            __builtin_amdgcn_s_barrier();
            __builtin_amdgcn_sched_barrier(0);
        }
    }
#undef CSTAGE

    const int mb = m0 + wr * 64, nb = n0 + wc * 64;
    size_t ob = (size_t)z * SEQ * D2;
#pragma unroll
    for (int i = 0; i < 4; ++i)
#pragma unroll
        for (int j = 0; j < 4; ++j)
#pragma unroll
            for (int r = 0; r < 4; ++r) {
                int mg = mb + i * 16 + l4 * 4 + r;
                int ng = nb + j * 16 + l15;
                float c = acc[i][j][r] + cb[mg];
                outp[ob + (size_t)mg * D2 + ng] =
                    __float2bfloat16(c * sigmoidf_(c));
            }
}

// ------------------------------------------------- bc via skinny MFMA GEMM
__global__ __launch_bounds__(256) void bc2_k(
    const __hip_bfloat16* __restrict__ u, const __hip_bfloat16* __restrict__ fcT,
    const float* __restrict__ b2, const float* __restrict__ b3,
    float* __restrict__ bc) {
    __shared__ __align__(16) __hip_bfloat16 Bl[32 * 1024];
    __shared__ __align__(16) __hip_bfloat16 As[3][128 * 32];
    const int m0 = blockIdx.x * 128;
    const int t = threadIdx.x, lane = t & 63, w = t >> 6;
    const int l15 = lane & 15, l4 = lane >> 4;

#pragma unroll
    for (int it = 0; it < 16; ++it) {
        int q = it * 256 + t;
        int n = q >> 7, blk = q & 127;
        uint4 v = *(const uint4*)(fcT + (size_t)n * 1024 + blk * 8);
        *(uint4*)&Bl[(n * 128 + (blk ^ (n & 7))) * 8] = v;
    }

    const int r0_ = t >> 2, c0_ = (t & 3) ^ ((r0_ >> 1) & 3);
    const int bq = 256 + t, r1_ = bq >> 2, c1_ = (bq & 3) ^ ((r1_ >> 1) & 3);
    const __hip_bfloat16* gA0 = u + (size_t)(m0 + r0_) * 1024 + c0_ * 8;
    const __hip_bfloat16* gA1 = u + (size_t)(m0 + r1_) * 1024 + c1_ * 8;
    const int d0 = (w * 64) * 8, d1 = (256 + w * 64) * 8;

    int offA[2];
#pragma unroll
    for (int i = 0; i < 2; ++i) {
        int ra = w * 32 + i * 16 + l15;
        offA[i] = (ra * 4 + (l4 ^ ((ra >> 1) & 3))) * 8;
    }

#define BSTAGE(BUF, K0)                  \
    {                                    \
        gll16(gA0 + (K0), &As[BUF][d0]); \
        gll16(gA1 + (K0), &As[BUF][d1]); \
    }

    f32x4 acc[2][2] = {};
    unsigned curb = 0, nxtb = 1, thdb = 2;
    BSTAGE(0, 0);
    BSTAGE(1, 32);
    asm volatile("s_waitcnt vmcnt(2)" ::: "memory");
    __builtin_amdgcn_s_barrier();
    __builtin_amdgcn_sched_barrier(0);

#pragma unroll 1
    for (int kt = 0; kt < 32; ++kt) {
        const bool st = (kt + 2 < 32);
        if (st) BSTAGE(thdb, (kt + 2) * 32);
        bf16x8 af[2], bf[2];
#pragma unroll
        for (int i = 0; i < 2; ++i) af[i] = *(const bf16x8*)&As[curb][offA[i]];
#pragma unroll
        for (int nj = 0; nj < 2; ++nj) {
            int n = nj * 16 + l15;
            int blk = (kt * 4 + l4) ^ (n & 7);
            bf[nj] = *(const bf16x8*)&Bl[(n * 128 + blk) * 8];
        }
#pragma unroll
        for (int i = 0; i < 2; ++i)
#pragma unroll
            for (int nj = 0; nj < 2; ++nj)
                acc[i][nj] = __builtin_amdgcn_mfma_f32_16x16x32_bf16(
                    af[i], bf[nj], acc[i][nj], 0, 0, 0);
        if (kt + 1 < 32) {
            if (st)
                asm volatile("s_waitcnt vmcnt(2)" ::: "memory");
            else
                asm volatile("s_waitcnt vmcnt(0)" ::: "memory");
            __builtin_amdgcn_s_barrier();
            __builtin_amdgcn_sched_barrier(0);
        }
        unsigned tb = curb;
        curb = nxtb;
        nxtb = thdb;
        thdb = tb;
    }
#undef BSTAGE

    float bb2 = b2[l15], bb3 = b3[l15];
#pragma unroll
    for (int i = 0; i < 2; ++i)
#pragma unroll
        for (int r = 0; r < 4; ++r) {
            float Bv = acc[i][0][r] + bb2;
            float Cv = acc[i][1][r] + bb3;
            float p = Bv * Cv;
            p += __shfl_xor(p, 1, 64);
            p += __shfl_xor(p, 2, 64);
            p += __shfl_xor(p, 4, 64);
            p += __shfl_xor(p, 8, 64);
            if (l15 == 0)
                bc[m0 + w * 32 + i * 16 + l4 * 4 + r] = p;
        }
}

// ----------------------------------------------------------------- launch
extern "C" void kernel_launch(void* const* d_in, const int* in_sizes, int n_in,
                              void* d_out, int out_size, void* d_ws,
                              size_t ws_size, hipStream_t stream) {
    const float* x = (const float*)d_in[0];
    const float* norm_w = (const float*)d_in[1];
    const float* inp_w = (const float*)d_in[2];
    const float* inp_b = (const float*)d_in[3];
    const float* conv_w = (const float*)d_in[4];
    const float* conv_b = (const float*)d_in[5];
    const float* convlin_w = (const float*)d_in[6];
    const float* convlin_b = (const float*)d_in[7];
    const float* fc1_w = (const float*)d_in[8];
    const float* fc1_b = (const float*)d_in[9];
    const float* fc2_w = (const float*)d_in[10];
    const float* fc2_b = (const float*)d_in[11];
    const float* fc3_w = (const float*)d_in[12];
    const float* fc3_b = (const float*)d_in[13];
    const float* D_w = (const float*)d_in[14];
    const float* D_b = (const float*)d_in[15];
    const float* out_w = (const float*)d_in[16];
    const float* out_b = (const float*)d_in[17];
    float* out = (float*)d_out;

    __hip_bfloat16* xnb = (__hip_bfloat16*)d_ws;          // [ROWS][DM]
    __hip_bfloat16* xt = xnb + (size_t)ROWS * DM;         // [B][D2][SEQ]
    __hip_bfloat16* cvo = xt + (size_t)BATCH * D2 * SEQ;  // conv out / act
    __hip_bfloat16* u = cvo + (size_t)ROWS * D2;          // [ROWS][D2]
    __hip_bfloat16* resid = u + (size_t)ROWS * D2;        // [ROWS][D2]
    __hip_bfloat16* Wcat = resid + (size_t)ROWS * D2;     // [2*D2][DM]
    __hip_bfloat16* clT = Wcat + (size_t)2 * D2 * DM;     // [D2][D2]
    __hip_bfloat16* fc1T = clT + (size_t)D2 * D2;         // [D2][D2]
    __hip_bfloat16* outT = fc1T + (size_t)D2 * D2;        // [DM][D2]
    __hip_bfloat16* wk = outT + (size_t)DM * D2;          // [3][SEQ][SEQ]
    __hip_bfloat16* fcT = wk + (size_t)3 * SEQ * SEQ;     // [32][D2]
    float* bcb = (float*)(fcT + (size_t)32 * D2);         // [ROWS]

    prep_all<<<dim3(32, 32, 7), 256, 0, stream>>>(
        inp_w, D_w, convlin_w, fc1_w, out_w, fc2_w, fc3_w, Wcat,
        Wcat + (size_t)D2 * DM, clT, fc1T, outT, fcT, fcT + (size_t)16 * D2);
    convw_k<<<SEQ * SEQ / 256, 256, 0, stream>>>(conv_w, wk);
    // 1. xn = rmsnorm(x) (bf16)
    rmsnorm_k<<<ROWS, 256, 0, stream>>>(x, norm_w, xnb);
    // 2+6. fused: x_proj -> Xt (transposed) AND resid = silu(xn@D_w+b)
    mgemm<5, DM><<<dim3(2 * D2 / 128, ROWS / 128), 256, 0, stream>>>(
        xnb, Wcat, inp_b, xt, resid, D_b, nullptr, nullptr, nullptr, ROWS,
        2 * D2);
    // 3. conv + bias + silu -> cvo[b][o][h]
    conv_mfma<<<dim3(D2 / 128, SEQ / 128, BATCH), 256, 0, stream>>>(
        wk, xt, conv_b, cvo);
    // 4. u = cvo @ convlin + b
    mgemm<1, D2><<<dim3(D2 / 128, ROWS / 128), 256, 0, stream>>>(
        cvo, clT, convlin_b, u, nullptr, nullptr, nullptr, nullptr, nullptr,
        ROWS, D2);
    // 5. bc via skinny MFMA
    bc2_k<<<ROWS / 128, 256, 0, stream>>>(u, fcT, fc2_b, fc3_b, bcb);
    // 7. delta GEMM + ssm tail -> act (reuses cvo)
    mgemm<3, D2><<<dim3(D2 / 128, ROWS / 128), 256, 0, stream>>>(
        u, fc1T, fc1_b, cvo, nullptr, nullptr, u, resid, bcb, ROWS, D2);
    // 8. out = act @ out_w + out_b (f32)
    mgemm<4, D2><<<dim3(DM / 128, ROWS / 128), 256, 0, stream>>>(
        cvo, outT, out_b, out, nullptr, nullptr, nullptr, nullptr, nullptr,
        ROWS, DM);
}